// Round 2
// baseline (281.019 us; speedup 1.0000x reference)
//
#include <hip/hip_runtime.h>
#include <math.h>

// Problem constants
#define NB   64      // batch
#define NPT  500     // entities == relations per image
#define C1   151     // classes incl. background
#define CM1  150     // kept classes
#define EAF  12      // ent aux floats/row {score,cx,cy,n2, x0,y0,x1,y1, area, w, h, pad}
#define RAF  20      // rel aux floats/row {rs box*4, ro box*4, vec*4, rsn2, ron2, aRs, aRo, rsW, rsH, roW, roH}

// Swizzled prob layout (bf16): [img][g=row/16][kb=k/8][ir=row%16][8]
#define GRP_ELEMS  2560
#define IMG_ELEMS  (32 * GRP_ELEMS)
#define PROB_ELEMS ((size_t)NB * IMG_ELEMS)

typedef __bf16 bf16x8 __attribute__((ext_vector_type(8)));
typedef float  f32x4  __attribute__((ext_vector_type(4)));

__device__ __forceinline__ float rcpf(float x) { return __builtin_amdgcn_rcpf(x); }
__device__ __forceinline__ float rsqf(float x) { return __builtin_amdgcn_rsqf(x); }

// ---------------------------------------------------------------------------
// Kernel 1: 16 lanes per row, 16 rows per block; block == one swizzled group.
// Probs staged in 5 KB LDS, then written as one contiguous 5120-B burst.
// ---------------------------------------------------------------------------
extern "C" __global__ void __launch_bounds__(256)
k_pre(const float* __restrict__ boxes, const float* __restrict__ ent_logits,
      const float* __restrict__ ro_logits, const float* __restrict__ rs_logits,
      const float* __restrict__ ro_box, const float* __restrict__ rs_box,
      const float* __restrict__ rel_vec, const float* __restrict__ tsz,
      __bf16* __restrict__ entP, __bf16* __restrict__ rsP, __bf16* __restrict__ roP,
      float* __restrict__ entAux, float* __restrict__ relAux)
{
    __shared__ __align__(16) __bf16 sP[GRP_ELEMS];   // 5120 B

    const int tid = threadIdx.x;
    const int q   = tid & 15;
    const int rl  = tid >> 4;
    const int bx  = blockIdx.x;
    const int set = bx >> 11;          // 2048 blocks per set
    const int rem = bx & 2047;
    const int b   = rem >> 5;          // image
    const int g   = rem & 31;          // group (16 rows)
    const int i   = g * 16 + rl;       // in-image row
    const bool valid = (i < NPT);      // group 31 has only 4 valid rows
    const int rowIdx = b * NPT + i;

    const float* src = (set == 0 ? ent_logits : (set == 1 ? rs_logits : ro_logits))
                       + (size_t)rowIdx * C1;

    float x[10];
    if (valid) {
        #pragma unroll
        for (int t = 0; t < 9; ++t) x[t] = src[q + 16 * t];
        x[9] = (q <= 6) ? src[q + 144] : -INFINITY;
    } else {
        #pragma unroll
        for (int t = 0; t < 9; ++t) x[t] = 0.f;
        x[9] = -INFINITY;
    }

    float mAll = x[0];
    #pragma unroll
    for (int t = 1; t < 10; ++t) mAll = fmaxf(mAll, x[t]);
    float mKept = x[0];
    #pragma unroll
    for (int t = 1; t < 9; ++t) mKept = fmaxf(mKept, x[t]);
    if (q <= 5) mKept = fmaxf(mKept, x[9]);

    #pragma unroll
    for (int off = 1; off < 16; off <<= 1) {
        mAll  = fmaxf(mAll,  __shfl_xor(mAll,  off, 16));
        mKept = fmaxf(mKept, __shfl_xor(mKept, off, 16));
    }

    float e[10], s = 0.f, s2 = 0.f;
    #pragma unroll
    for (int t = 0; t < 9; ++t) {
        e[t] = __expf(x[t] - mAll);
        s  += e[t];
        s2 += e[t] * e[t];
    }
    e[9] = (q <= 6) ? __expf(x[9] - mAll) : 0.f;
    s += e[9];
    if (q <= 5) s2 += e[9] * e[9];

    #pragma unroll
    for (int off = 1; off < 16; off <<= 1) {
        s  += __shfl_xor(s,  off, 16);
        s2 += __shfl_xor(s2, off, 16);
    }

    const float inv = rcpf(s);
    const float pm  = __expf(mKept - mAll) * inv;
    const float nn  = s2 * inv * inv;

    // ---- stage probs to LDS (block == one contiguous group) ----
    const int base = rl * 8 + (q & 7);
    const int qh   = q >> 3;
    #pragma unroll
    for (int t = 0; t < 9; ++t)
        sP[(2 * t + qh) * 128 + base] = valid ? (__bf16)(e[t] * inv) : (__bf16)0.f;
    sP[(18 + qh) * 128 + base] = (valid && q <= 5) ? (__bf16)(e[9] * inv) : (__bf16)0.f;

    if (q == 0 && valid) {
        const float hh = tsz[b * 2 + 0];
        const float ww = tsz[b * 2 + 1];
        if (set == 0) {
            const float* bb = boxes + (size_t)rowIdx * 4;
            const float cx = bb[0], cy = bb[1], bw = bb[2], bh = bb[3];
            const float X0 = (cx - 0.5f * bw) * ww, Y0 = (cy - 0.5f * bh) * hh;
            const float X1 = (cx + 0.5f * bw) * ww, Y1 = (cy + 0.5f * bh) * hh;
            float* A = entAux + (size_t)rowIdx * EAF;
            A[0] = pm;
            A[1] = 0.5f * (X0 + X1);
            A[2] = 0.5f * (Y0 + Y1);
            A[3] = nn;
            A[4] = X0; A[5] = Y0; A[6] = X1; A[7] = Y1;
            A[8] = (X1 - X0) * (Y1 - Y0);
            A[9] = X1 - X0;          // eW
            A[10] = Y1 - Y0;         // eH
        } else if (set == 1) {
            const float* bb = rs_box  + (size_t)rowIdx * 4;
            const float* vv = rel_vec + (size_t)rowIdx * 4;
            const float cx = bb[0], cy = bb[1], bw = bb[2], bh = bb[3];
            float* A = relAux + (size_t)rowIdx * RAF;
            const float X0 = (cx - 0.5f * bw) * ww, Y0 = (cy - 0.5f * bh) * hh;
            const float X1 = (cx + 0.5f * bw) * ww, Y1 = (cy + 0.5f * bh) * hh;
            A[0] = X0; A[1] = Y0; A[2] = X1; A[3] = Y1;
            A[8]  = vv[0] * ww; A[9]  = vv[1] * hh;
            A[10] = vv[2] * ww; A[11] = vv[3] * hh;
            A[12] = nn;
            A[14] = (X1 - X0) * (Y1 - Y0);
            A[16] = X1 - X0;         // rsW
            A[17] = Y1 - Y0;         // rsH
        } else {
            const float* bb = ro_box + (size_t)rowIdx * 4;
            const float cx = bb[0], cy = bb[1], bw = bb[2], bh = bb[3];
            float* A = relAux + (size_t)rowIdx * RAF;
            const float X0 = (cx - 0.5f * bw) * ww, Y0 = (cy - 0.5f * bh) * hh;
            const float X1 = (cx + 0.5f * bw) * ww, Y1 = (cy + 0.5f * bh) * hh;
            A[4] = X0; A[5] = Y0; A[6] = X1; A[7] = Y1;
            A[13] = nn;
            A[15] = (X1 - X0) * (Y1 - Y0);
            A[18] = X1 - X0;         // roW
            A[19] = Y1 - Y0;         // roH
        }
    }

    __syncthreads();

    // ---- contiguous coalesced group write: 5120 B = 320 x float4 ----
    __bf16* dstT = (set == 0 ? entP : (set == 1 ? rsP : roP));
    float4* dstG = (float4*)(dstT + ((size_t)b * 32 + g) * GRP_ELEMS);
    const float4* srcL = (const float4*)sP;
    dstG[tid] = srcL[tid];
    if (tid < 64) dstG[256 + tid] = srcL[256 + tid];
}

// ---------------------------------------------------------------------------
// Epilogue: width-trick enclosure (min+max=sum) + single-rcp merge:
//   v = max(score*(in*aC + un^2 - un*aC), 0) * rcp(un*aC*(dist+1)*(d+1))
// Nontemporal out stores (write-once stream; keep L2 for prob reads).
// ---------------------------------------------------------------------------
template <bool FULL>
__device__ __forceinline__ void epilogue(
    const float (*eA)[EAF], const float (*rA)[RAF],
    const f32x4* accS, const f32x4* accO,
    int lr, int kq, int wv, int b, int e0T, int r0T,
    float* __restrict__ outS, float* __restrict__ outO)
{
    f32x4 ev0[4], ev1[4];
    float eAr[4], eW[4], eH[4];
    #pragma unroll
    for (int et = 0; et < 4; ++et) {
        const float* ep = eA[et * 16 + lr];
        ev0[et] = *(const f32x4*)(ep);       // score, cx, cy, n2
        ev1[et] = *(const f32x4*)(ep + 4);   // x0, y0, x1, y1
        eAr[et] = ep[8]; eW[et] = ep[9]; eH[et] = ep[10];
    }

    const unsigned baseR0 = ((unsigned)b * NPT + (unsigned)(r0T + wv * 16 + kq * 4)) * NPT;
    const unsigned eBase  = (unsigned)(e0T + lr);

    #pragma unroll
    for (int reg = 0; reg < 4; ++reg) {
        const int rIdx = wv * 16 + kq * 4 + reg;
        const bool rOK = FULL || (r0T + rIdx < NPT);
        const float* rp = rA[rIdx];
        const f32x4 rsB = *(const f32x4*)(rp);        // rs box
        const f32x4 roB = *(const f32x4*)(rp + 4);    // ro box
        const f32x4 vv  = *(const f32x4*)(rp + 8);    // vec: sx, sy, ox, oy
        const f32x4 rn  = *(const f32x4*)(rp + 12);   // rsn2, ron2, areaRs, areaRo
        const f32x4 rw  = *(const f32x4*)(rp + 16);   // rsW, rsH, roW, roH
        const unsigned rowOff = baseR0 + (unsigned)reg * NPT;

        #pragma unroll
        for (int et = 0; et < 4; ++et) {
            const float score = ev0[et][0], ecx = ev0[et][1], ecy = ev0[et][2], en2 = ev0[et][3];
            const float ex0 = ev1[et][0], ey0 = ev1[et][1], ex1 = ev1[et][2], ey1 = ev1[et][3];
            const float aE = eAr[et];

            // ---- S side ----
            const float iwrS = fminf(ex1, rsB[2]) - fmaxf(ex0, rsB[0]);
            const float ihrS = fminf(ey1, rsB[3]) - fmaxf(ey0, rsB[1]);
            const float inS  = fmaxf(iwrS, 0.f) * fmaxf(ihrS, 0.f);
            const float aCS  = ((eW[et] + rw[0]) - iwrS) * ((eH[et] + rw[1]) - ihrS);
            const float unS  = (aE + rn[2]) - inS;
            const float uaS  = unS * aCS;
            const float numS = fmaxf(score * (fmaf(inS, aCS, unS * unS) - uaS), 0.f);
            const float d2s  = fmaxf(fmaf(-2.f, accS[et][reg], rn[0] + en2), 1e-12f);
            const float dS   = d2s * rsqf(d2s);
            const float distS= fabsf(vv[0] - ecx) + fabsf(vv[1] - ecy);
            const float vS   = numS * rcpf(uaS * (distS + 1.f) * (dS + 1.f));

            // ---- O side ----
            const float iwrO = fminf(ex1, roB[2]) - fmaxf(ex0, roB[0]);
            const float ihrO = fminf(ey1, roB[3]) - fmaxf(ey0, roB[1]);
            const float inO  = fmaxf(iwrO, 0.f) * fmaxf(ihrO, 0.f);
            const float aCO  = ((eW[et] + rw[2]) - iwrO) * ((eH[et] + rw[3]) - ihrO);
            const float unO  = (aE + rn[3]) - inO;
            const float uaO  = unO * aCO;
            const float numO = fmaxf(score * (fmaf(inO, aCO, unO * unO) - uaO), 0.f);
            const float d2o  = fmaxf(fmaf(-2.f, accO[et][reg], rn[1] + en2), 1e-12f);
            const float dO   = d2o * rsqf(d2o);
            const float distO= fabsf(vv[2] - ecx) + fabsf(vv[3] - ecy);
            const float vO   = numO * rcpf(uaO * (distO + 1.f) * (dO + 1.f));

            const unsigned o = rowOff + eBase + (unsigned)(et * 16);
            if (FULL || (rOK && (int)(eBase + et * 16) < NPT)) {
                __builtin_nontemporal_store(vS, &outS[o]);
                __builtin_nontemporal_store(vO, &outO[o]);
            }
        }
    }
}

// ---------------------------------------------------------------------------
// Kernel 2, R8: 64r x 128e tile per block (grid 64 x 32). Rel fragments
// (ars/aro, 40 VGPR) loaded ONCE and reused across two 64-col ent subtiles
// -> rel read stream halves (164 -> 82 MB). Ent tile: 8 contiguous groups
// (40 KB) staged via async global_load_lds. Dual acc sets (64 VGPR) so the
// K-loop finishes both subtiles and releases ars/aro before the epilogues.
// LDS 51 KB -> 3 blocks/CU; __launch_bounds__(256,3) keeps VGPR cap ~168
// (epilogue peak ~140 regs; a 128 cap would spill).
// ---------------------------------------------------------------------------
extern "C" __global__ void __launch_bounds__(256, 3)
k_main(const __bf16* __restrict__ entP, const __bf16* __restrict__ rsP,
       const __bf16* __restrict__ roP, const float* __restrict__ eAuxG,
       const float* __restrict__ rAuxG,
       float* __restrict__ outS, float* __restrict__ outO)
{
    __shared__ __align__(16) __bf16 sEnt[8 * GRP_ELEMS];   // 40 KB (2 subtiles)
    __shared__ __align__(16) float eA[128][EAF];           // 6 KB
    __shared__ __align__(16) float rA[64][RAF];            // 5 KB

    const int tid = threadIdx.x;
    const int b   = blockIdx.x;
    const int e0T = (blockIdx.y & 3) * 128;    // e-tile of 128
    const int r0T = (blockIdx.y >> 2) * 64;    // r-tile of 64

    const int wv   = tid >> 6;
    const int lane = tid & 63;
    const int lr   = lane & 15;
    const int kq   = lane >> 4;

    const int gR = (r0T >> 4) + wv;
    const int gE = (e0T >> 4);
    const __bf16* rsBase = rsP  + ((size_t)b * 32 + gR) * GRP_ELEMS + lr * 8;
    const __bf16* roBase = roP  + ((size_t)b * 32 + gR) * GRP_ELEMS + lr * 8;
    const __bf16* entSrc = entP + ((size_t)b * 32 + gE) * GRP_ELEMS;   // 40960 B contiguous

    // ---- hoist rel-side fragment loads (A operand, 10 x 16 B per lane) ----
    bf16x8 ars[5], aro[5];
    #pragma unroll
    for (int ks = 0; ks < 5; ++ks) {
        const int kOff = (ks * 4 + kq) * 128;
        ars[ks] = *(const bf16x8*)(rsBase + kOff);
        aro[ks] = *(const bf16x8*)(roBase + kOff);
    }

    // ---- async stage ent tile to LDS: 10 iters x (4 waves x 1 KB) = 40 KB ----
    #pragma unroll
    for (int it = 0; it < 10; ++it) {
        const int off = it * 4096 + wv * 1024;            // wave-uniform byte offset
        __builtin_amdgcn_global_load_lds(
            (const __attribute__((address_space(1))) unsigned int*)
                ((const char*)entSrc + off + lane * 16),
            (__attribute__((address_space(3))) unsigned int*)
                ((char*)sEnt + off),
            16, 0, 0);
    }

    // ---- stage aux to LDS ----
    {
        const float4 z = {0.f, 0.f, 0.f, 0.f};
        for (int t = tid; t < 128 * (EAF / 4); t += 256) {
            const int e = t / (EAF / 4), qq = t % (EAF / 4);
            const int ge = e0T + e;
            ((float4*)eA[e])[qq] = (ge < NPT)
                ? ((const float4*)(eAuxG + ((size_t)b * NPT + ge) * EAF))[qq] : z;
        }
        for (int t = tid; t < 64 * (RAF / 4); t += 256) {
            const int r = t / (RAF / 4), qq = t % (RAF / 4);
            const int gr = r0T + r;
            ((float4*)rA[r])[qq] = (gr < NPT)
                ? ((const float4*)(rAuxG + ((size_t)b * NPT + gr) * RAF))[qq] : z;
        }
    }
    __syncthreads();   // drains vmcnt (incl. global_load_lds) + barrier

    f32x4 accS0[4] = {{0,0,0,0},{0,0,0,0},{0,0,0,0},{0,0,0,0}};
    f32x4 accO0[4] = {{0,0,0,0},{0,0,0,0},{0,0,0,0},{0,0,0,0}};
    f32x4 accS1[4] = {{0,0,0,0},{0,0,0,0},{0,0,0,0},{0,0,0,0}};
    f32x4 accO1[4] = {{0,0,0,0},{0,0,0,0},{0,0,0,0},{0,0,0,0}};

    #pragma unroll
    for (int ks = 0; ks < 5; ++ks) {
        const int kOff = (ks * 4 + kq) * 128 + lr * 8;
        #pragma unroll
        for (int et = 0; et < 4; ++et) {
            const bf16x8 be0 = *(const bf16x8*)&sEnt[et * GRP_ELEMS + kOff];
            const bf16x8 be1 = *(const bf16x8*)&sEnt[(4 + et) * GRP_ELEMS + kOff];
            accS0[et] = __builtin_amdgcn_mfma_f32_16x16x32_bf16(ars[ks], be0, accS0[et], 0, 0, 0);
            accO0[et] = __builtin_amdgcn_mfma_f32_16x16x32_bf16(aro[ks], be0, accO0[et], 0, 0, 0);
            accS1[et] = __builtin_amdgcn_mfma_f32_16x16x32_bf16(ars[ks], be1, accS1[et], 0, 0, 0);
            accO1[et] = __builtin_amdgcn_mfma_f32_16x16x32_bf16(aro[ks], be1, accO1[et], 0, 0, 0);
        }
    }

    // subtile 0 (cols e0T..e0T+63): FULL whenever the r-tile is full
    // (e0T+64 <= 500 holds for all four e-tiles: max 384+64 = 448).
    const bool rFull = (r0T + 64 <= NPT);
    if (rFull) {
        epilogue<true >(eA, rA, accS0, accO0, lr, kq, wv, b, e0T, r0T, outS, outO);
    } else {
        epilogue<false>(eA, rA, accS0, accO0, lr, kq, wv, b, e0T, r0T, outS, outO);
    }
    // subtile 1 (cols e0T+64..e0T+127): partial only in the last e-tile.
    if (rFull && e0T + 128 <= NPT) {
        epilogue<true >(&eA[64], rA, accS1, accO1, lr, kq, wv, b, e0T + 64, r0T, outS, outO);
    } else {
        epilogue<false>(&eA[64], rA, accS1, accO1, lr, kq, wv, b, e0T + 64, r0T, outS, outO);
    }
}

// ---------------------------------------------------------------------------
extern "C" void kernel_launch(void* const* d_in, const int* in_sizes, int n_in,
                              void* d_out, int out_size, void* d_ws, size_t ws_size,
                              hipStream_t stream)
{
    const float* boxes      = (const float*)d_in[0];
    const float* ent_logits = (const float*)d_in[1];
    const float* ro_logits  = (const float*)d_in[2];
    const float* rs_logits  = (const float*)d_in[3];
    const float* ro_box     = (const float*)d_in[4];
    const float* rs_box     = (const float*)d_in[5];
    const float* rel_vec    = (const float*)d_in[6];
    const float* tsz        = (const float*)d_in[7];

    __bf16* entP = (__bf16*)d_ws;
    __bf16* rsP  = entP + PROB_ELEMS;
    __bf16* roP  = rsP  + PROB_ELEMS;
    float*  eAux = (float*)(roP + PROB_ELEMS);
    float*  rAux = eAux + (size_t)NB * NPT * EAF;

    float* outS = (float*)d_out;
    float* outO = outS + (size_t)NB * NPT * NPT;

    hipLaunchKernelGGL(k_pre, dim3(6144), dim3(256), 0, stream,
                       boxes, ent_logits, ro_logits, rs_logits,
                       ro_box, rs_box, rel_vec, tsz,
                       entP, rsP, roP, eAux, rAux);

    hipLaunchKernelGGL(k_main, dim3(64, 32), dim3(256), 0, stream,
                       entP, rsP, roP, eAux, rAux, outS, outO);
}

// Round 3
// 231.027 us; speedup vs baseline: 1.2164x; 1.2164x over previous
//
#include <hip/hip_runtime.h>
#include <math.h>

// Problem constants
#define NB   64      // batch
#define NPT  500     // entities == relations per image
#define C1   151     // classes incl. background
#define CM1  150     // kept classes
#define EAF  12      // ent aux floats/row {score,cx,cy,n2, x0,y0,x1,y1, area, w, h, pad}
#define RAF  20      // rel aux floats/row {rs box*4, ro box*4, vec*4, rsn2, ron2, aRs, aRo, rsW, rsH, roW, roH}

// Swizzled prob layout (bf16): [img][g=row/16][kb=k/8][ir=row%16][8]
#define GRP_ELEMS  2560
#define IMG_ELEMS  (32 * GRP_ELEMS)
#define PROB_ELEMS ((size_t)NB * IMG_ELEMS)

typedef __bf16 bf16x8 __attribute__((ext_vector_type(8)));
typedef float  f32x4  __attribute__((ext_vector_type(4)));

__device__ __forceinline__ float rcpf(float x) { return __builtin_amdgcn_rcpf(x); }
__device__ __forceinline__ float rsqf(float x) { return __builtin_amdgcn_rsqf(x); }

// ---------------------------------------------------------------------------
// Kernel 1: 16 lanes per row, 16 rows per block; block == one swizzled group.
// Probs staged in 5 KB LDS, then written as one contiguous 5120-B burst.
// ---------------------------------------------------------------------------
extern "C" __global__ void __launch_bounds__(256)
k_pre(const float* __restrict__ boxes, const float* __restrict__ ent_logits,
      const float* __restrict__ ro_logits, const float* __restrict__ rs_logits,
      const float* __restrict__ ro_box, const float* __restrict__ rs_box,
      const float* __restrict__ rel_vec, const float* __restrict__ tsz,
      __bf16* __restrict__ entP, __bf16* __restrict__ rsP, __bf16* __restrict__ roP,
      float* __restrict__ entAux, float* __restrict__ relAux)
{
    __shared__ __align__(16) __bf16 sP[GRP_ELEMS];   // 5120 B

    const int tid = threadIdx.x;
    const int q   = tid & 15;
    const int rl  = tid >> 4;
    const int bx  = blockIdx.x;
    const int set = bx >> 11;          // 2048 blocks per set
    const int rem = bx & 2047;
    const int b   = rem >> 5;          // image
    const int g   = rem & 31;          // group (16 rows)
    const int i   = g * 16 + rl;       // in-image row
    const bool valid = (i < NPT);      // group 31 has only 4 valid rows
    const int rowIdx = b * NPT + i;

    const float* src = (set == 0 ? ent_logits : (set == 1 ? rs_logits : ro_logits))
                       + (size_t)rowIdx * C1;

    float x[10];
    if (valid) {
        #pragma unroll
        for (int t = 0; t < 9; ++t) x[t] = src[q + 16 * t];
        x[9] = (q <= 6) ? src[q + 144] : -INFINITY;
    } else {
        #pragma unroll
        for (int t = 0; t < 9; ++t) x[t] = 0.f;
        x[9] = -INFINITY;
    }

    float mAll = x[0];
    #pragma unroll
    for (int t = 1; t < 10; ++t) mAll = fmaxf(mAll, x[t]);
    float mKept = x[0];
    #pragma unroll
    for (int t = 1; t < 9; ++t) mKept = fmaxf(mKept, x[t]);
    if (q <= 5) mKept = fmaxf(mKept, x[9]);

    #pragma unroll
    for (int off = 1; off < 16; off <<= 1) {
        mAll  = fmaxf(mAll,  __shfl_xor(mAll,  off, 16));
        mKept = fmaxf(mKept, __shfl_xor(mKept, off, 16));
    }

    float e[10], s = 0.f, s2 = 0.f;
    #pragma unroll
    for (int t = 0; t < 9; ++t) {
        e[t] = __expf(x[t] - mAll);
        s  += e[t];
        s2 += e[t] * e[t];
    }
    e[9] = (q <= 6) ? __expf(x[9] - mAll) : 0.f;
    s += e[9];
    if (q <= 5) s2 += e[9] * e[9];

    #pragma unroll
    for (int off = 1; off < 16; off <<= 1) {
        s  += __shfl_xor(s,  off, 16);
        s2 += __shfl_xor(s2, off, 16);
    }

    const float inv = rcpf(s);
    const float pm  = __expf(mKept - mAll) * inv;
    const float nn  = s2 * inv * inv;

    // ---- stage probs to LDS (block == one contiguous group) ----
    const int base = rl * 8 + (q & 7);
    const int qh   = q >> 3;
    #pragma unroll
    for (int t = 0; t < 9; ++t)
        sP[(2 * t + qh) * 128 + base] = valid ? (__bf16)(e[t] * inv) : (__bf16)0.f;
    sP[(18 + qh) * 128 + base] = (valid && q <= 5) ? (__bf16)(e[9] * inv) : (__bf16)0.f;

    if (q == 0 && valid) {
        const float hh = tsz[b * 2 + 0];
        const float ww = tsz[b * 2 + 1];
        if (set == 0) {
            const float* bb = boxes + (size_t)rowIdx * 4;
            const float cx = bb[0], cy = bb[1], bw = bb[2], bh = bb[3];
            const float X0 = (cx - 0.5f * bw) * ww, Y0 = (cy - 0.5f * bh) * hh;
            const float X1 = (cx + 0.5f * bw) * ww, Y1 = (cy + 0.5f * bh) * hh;
            float* A = entAux + (size_t)rowIdx * EAF;
            A[0] = pm;
            A[1] = 0.5f * (X0 + X1);
            A[2] = 0.5f * (Y0 + Y1);
            A[3] = nn;
            A[4] = X0; A[5] = Y0; A[6] = X1; A[7] = Y1;
            A[8] = (X1 - X0) * (Y1 - Y0);
            A[9] = X1 - X0;          // eW
            A[10] = Y1 - Y0;         // eH
        } else if (set == 1) {
            const float* bb = rs_box  + (size_t)rowIdx * 4;
            const float* vv = rel_vec + (size_t)rowIdx * 4;
            const float cx = bb[0], cy = bb[1], bw = bb[2], bh = bb[3];
            float* A = relAux + (size_t)rowIdx * RAF;
            const float X0 = (cx - 0.5f * bw) * ww, Y0 = (cy - 0.5f * bh) * hh;
            const float X1 = (cx + 0.5f * bw) * ww, Y1 = (cy + 0.5f * bh) * hh;
            A[0] = X0; A[1] = Y0; A[2] = X1; A[3] = Y1;
            A[8]  = vv[0] * ww; A[9]  = vv[1] * hh;
            A[10] = vv[2] * ww; A[11] = vv[3] * hh;
            A[12] = nn;
            A[14] = (X1 - X0) * (Y1 - Y0);
            A[16] = X1 - X0;         // rsW
            A[17] = Y1 - Y0;         // rsH
        } else {
            const float* bb = ro_box + (size_t)rowIdx * 4;
            const float cx = bb[0], cy = bb[1], bw = bb[2], bh = bb[3];
            float* A = relAux + (size_t)rowIdx * RAF;
            const float X0 = (cx - 0.5f * bw) * ww, Y0 = (cy - 0.5f * bh) * hh;
            const float X1 = (cx + 0.5f * bw) * ww, Y1 = (cy + 0.5f * bh) * hh;
            A[4] = X0; A[5] = Y0; A[6] = X1; A[7] = Y1;
            A[13] = nn;
            A[15] = (X1 - X0) * (Y1 - Y0);
            A[18] = X1 - X0;         // roW
            A[19] = Y1 - Y0;         // roH
        }
    }

    __syncthreads();

    // ---- contiguous coalesced group write: 5120 B = 320 x float4 ----
    __bf16* dstT = (set == 0 ? entP : (set == 1 ? rsP : roP));
    float4* dstG = (float4*)(dstT + ((size_t)b * 32 + g) * GRP_ELEMS);
    const float4* srcL = (const float4*)sP;
    dstG[tid] = srcL[tid];
    if (tid < 64) dstG[256 + tid] = srcL[256 + tid];
}

// ---------------------------------------------------------------------------
// Epilogue: width-trick enclosure (min+max=sum) + single-rcp merge:
//   v = max(score*(in*aC + un^2 - un*aC), 0) * rcp(un*aC*(dist+1)*(d+1))
// Plain stores (R8 post-mortem: nontemporal stores dropped write BW to
// ~1.9 TB/s vs ~6.4 for the same pattern through L2 — do NOT use NT here).
// ---------------------------------------------------------------------------
template <bool FULL>
__device__ __forceinline__ void epilogue(
    const float (*eA)[EAF], const float (*rA)[RAF],
    const f32x4* accS, const f32x4* accO,
    int lr, int kq, int wv, int b, int e0T, int r0T,
    float* __restrict__ outS, float* __restrict__ outO)
{
    f32x4 ev0[4], ev1[4];
    float eAr[4], eW[4], eH[4];
    #pragma unroll
    for (int et = 0; et < 4; ++et) {
        const float* ep = eA[et * 16 + lr];
        ev0[et] = *(const f32x4*)(ep);       // score, cx, cy, n2
        ev1[et] = *(const f32x4*)(ep + 4);   // x0, y0, x1, y1
        eAr[et] = ep[8]; eW[et] = ep[9]; eH[et] = ep[10];
    }

    const unsigned baseR0 = ((unsigned)b * NPT + (unsigned)(r0T + wv * 16 + kq * 4)) * NPT;
    const unsigned eBase  = (unsigned)(e0T + lr);

    #pragma unroll
    for (int reg = 0; reg < 4; ++reg) {
        const int rIdx = wv * 16 + kq * 4 + reg;
        const bool rOK = FULL || (r0T + rIdx < NPT);
        const float* rp = rA[rIdx];
        const f32x4 rsB = *(const f32x4*)(rp);        // rs box
        const f32x4 roB = *(const f32x4*)(rp + 4);    // ro box
        const f32x4 vv  = *(const f32x4*)(rp + 8);    // vec: sx, sy, ox, oy
        const f32x4 rn  = *(const f32x4*)(rp + 12);   // rsn2, ron2, areaRs, areaRo
        const f32x4 rw  = *(const f32x4*)(rp + 16);   // rsW, rsH, roW, roH
        const unsigned rowOff = baseR0 + (unsigned)reg * NPT;

        #pragma unroll
        for (int et = 0; et < 4; ++et) {
            const float score = ev0[et][0], ecx = ev0[et][1], ecy = ev0[et][2], en2 = ev0[et][3];
            const float ex0 = ev1[et][0], ey0 = ev1[et][1], ex1 = ev1[et][2], ey1 = ev1[et][3];
            const float aE = eAr[et];

            // ---- S side ----
            const float iwrS = fminf(ex1, rsB[2]) - fmaxf(ex0, rsB[0]);
            const float ihrS = fminf(ey1, rsB[3]) - fmaxf(ey0, rsB[1]);
            const float inS  = fmaxf(iwrS, 0.f) * fmaxf(ihrS, 0.f);
            const float aCS  = ((eW[et] + rw[0]) - iwrS) * ((eH[et] + rw[1]) - ihrS);
            const float unS  = (aE + rn[2]) - inS;
            const float uaS  = unS * aCS;
            const float numS = fmaxf(score * (fmaf(inS, aCS, unS * unS) - uaS), 0.f);
            const float d2s  = fmaxf(fmaf(-2.f, accS[et][reg], rn[0] + en2), 1e-12f);
            const float dS   = d2s * rsqf(d2s);
            const float distS= fabsf(vv[0] - ecx) + fabsf(vv[1] - ecy);
            const float vS   = numS * rcpf(uaS * (distS + 1.f) * (dS + 1.f));

            // ---- O side ----
            const float iwrO = fminf(ex1, roB[2]) - fmaxf(ex0, roB[0]);
            const float ihrO = fminf(ey1, roB[3]) - fmaxf(ey0, roB[1]);
            const float inO  = fmaxf(iwrO, 0.f) * fmaxf(ihrO, 0.f);
            const float aCO  = ((eW[et] + rw[2]) - iwrO) * ((eH[et] + rw[3]) - ihrO);
            const float unO  = (aE + rn[3]) - inO;
            const float uaO  = unO * aCO;
            const float numO = fmaxf(score * (fmaf(inO, aCO, unO * unO) - uaO), 0.f);
            const float d2o  = fmaxf(fmaf(-2.f, accO[et][reg], rn[1] + en2), 1e-12f);
            const float dO   = d2o * rsqf(d2o);
            const float distO= fabsf(vv[2] - ecx) + fabsf(vv[3] - ecy);
            const float vO   = numO * rcpf(uaO * (distO + 1.f) * (dO + 1.f));

            const unsigned o = rowOff + eBase + (unsigned)(et * 16);
            if (FULL || (rOK && (int)(eBase + et * 16) < NPT)) {
                outS[o] = vS;
                outO[o] = vO;
            }
        }
    }
}

// ---------------------------------------------------------------------------
// Kernel 2, R9: back to 64r x 64e tile (grid 64 x 64), and the ent-side
// B fragments are loaded DIRECTLY global->reg instead of via an LDS stage.
// Rationale (R8 counters): FETCH_SIZE was 17.9 MB -> prob data is fully
// L2/L3-resident, so the LDS tile only provided a 4x L2-traffic reduction
// (~240 MB extra L2 reads ~ 7 us of 34 TB/s L2 BW, overlappable) while
// costing a serial 20 KB global->LDS drain + barrier before any MFMA.
// Per-wave be load = 1 KB contiguous, perfectly coalesced (same pattern as
// the rel fragment loads). LDS now 8 KB (aux only).
// ---------------------------------------------------------------------------
extern "C" __global__ void __launch_bounds__(256, 4)
k_main(const __bf16* __restrict__ entP, const __bf16* __restrict__ rsP,
       const __bf16* __restrict__ roP, const float* __restrict__ eAuxG,
       const float* __restrict__ rAuxG,
       float* __restrict__ outS, float* __restrict__ outO)
{
    __shared__ __align__(16) float eA[64][EAF];   // 3 KB
    __shared__ __align__(16) float rA[64][RAF];   // 5 KB

    const int tid = threadIdx.x;
    const int b   = blockIdx.x;
    const int e0T = (blockIdx.y & 7) * 64;
    const int r0T = (blockIdx.y >> 3) * 64;

    const int wv   = tid >> 6;
    const int lane = tid & 63;
    const int lr   = lane & 15;
    const int kq   = lane >> 4;

    const int gR = (r0T >> 4) + wv;
    const int gE = (e0T >> 4);
    const __bf16* rsBase  = rsP  + ((size_t)b * 32 + gR) * GRP_ELEMS + lr * 8;
    const __bf16* roBase  = roP  + ((size_t)b * 32 + gR) * GRP_ELEMS + lr * 8;
    const __bf16* entBase = entP + ((size_t)b * 32 + gE) * GRP_ELEMS + lr * 8;

    // ---- hoist rel-side fragment loads (A operand, 10 x 16 B per lane) ----
    bf16x8 ars[5], aro[5];
    #pragma unroll
    for (int ks = 0; ks < 5; ++ks) {
        const int kOff = (ks * 4 + kq) * 128;
        ars[ks] = *(const bf16x8*)(rsBase + kOff);
        aro[ks] = *(const bf16x8*)(roBase + kOff);
    }

    // ---- stage aux to LDS ----
    {
        const float4 z = {0.f, 0.f, 0.f, 0.f};
        for (int t = tid; t < 64 * (EAF / 4); t += 256) {
            const int e = t / (EAF / 4), qq = t % (EAF / 4);
            const int ge = e0T + e;
            ((float4*)eA[e])[qq] = (ge < NPT)
                ? ((const float4*)(eAuxG + ((size_t)b * NPT + ge) * EAF))[qq] : z;
        }
        for (int t = tid; t < 64 * (RAF / 4); t += 256) {
            const int r = t / (RAF / 4), qq = t % (RAF / 4);
            const int gr = r0T + r;
            ((float4*)rA[r])[qq] = (gr < NPT)
                ? ((const float4*)(rAuxG + ((size_t)b * NPT + gr) * RAF))[qq] : z;
        }
    }
    __syncthreads();

    f32x4 accS[4] = {{0,0,0,0},{0,0,0,0},{0,0,0,0},{0,0,0,0}};
    f32x4 accO[4] = {{0,0,0,0},{0,0,0,0},{0,0,0,0},{0,0,0,0}};

    #pragma unroll
    for (int ks = 0; ks < 5; ++ks) {
        const int kOff = (ks * 4 + kq) * 128;
        #pragma unroll
        for (int et = 0; et < 4; ++et) {
            const bf16x8 be = *(const bf16x8*)(entBase + et * GRP_ELEMS + kOff);
            accS[et] = __builtin_amdgcn_mfma_f32_16x16x32_bf16(ars[ks], be, accS[et], 0, 0, 0);
            accO[et] = __builtin_amdgcn_mfma_f32_16x16x32_bf16(aro[ks], be, accO[et], 0, 0, 0);
        }
    }

    if (e0T + 64 <= NPT && r0T + 64 <= NPT) {
        epilogue<true >(eA, rA, accS, accO, lr, kq, wv, b, e0T, r0T, outS, outO);
    } else {
        epilogue<false>(eA, rA, accS, accO, lr, kq, wv, b, e0T, r0T, outS, outO);
    }
}

// ---------------------------------------------------------------------------
extern "C" void kernel_launch(void* const* d_in, const int* in_sizes, int n_in,
                              void* d_out, int out_size, void* d_ws, size_t ws_size,
                              hipStream_t stream)
{
    const float* boxes      = (const float*)d_in[0];
    const float* ent_logits = (const float*)d_in[1];
    const float* ro_logits  = (const float*)d_in[2];
    const float* rs_logits  = (const float*)d_in[3];
    const float* ro_box     = (const float*)d_in[4];
    const float* rs_box     = (const float*)d_in[5];
    const float* rel_vec    = (const float*)d_in[6];
    const float* tsz        = (const float*)d_in[7];

    __bf16* entP = (__bf16*)d_ws;
    __bf16* rsP  = entP + PROB_ELEMS;
    __bf16* roP  = rsP  + PROB_ELEMS;
    float*  eAux = (float*)(roP + PROB_ELEMS);
    float*  rAux = eAux + (size_t)NB * NPT * EAF;

    float* outS = (float*)d_out;
    float* outO = outS + (size_t)NB * NPT * NPT;

    hipLaunchKernelGGL(k_pre, dim3(6144), dim3(256), 0, stream,
                       boxes, ent_logits, ro_logits, rs_logits,
                       ro_box, rs_box, rel_vec, tsz,
                       entP, rsP, roP, eAux, rAux);

    hipLaunchKernelGGL(k_main, dim3(64, 64), dim3(256), 0, stream,
                       entP, rsP, roP, eAux, rAux, outS, outO);
}